// Round 14
// baseline (239.678 us; speedup 1.0000x reference)
//
#include <hip/hip_runtime.h>

#define NN 50000
#define NE 800000
#define HID 128
#define OUTD 64
#define NBK 200      // buckets (dst-partition)
#define BWID 250     // nodes per bucket
#define CAP 5120     // padded capacity per bucket (mean 4000, +17 sigma)
#define TILE_E 4096  // edges per binA block
#define XB 3125      // NN*16/256 exact
#define HB 196       // ceil(NE/TILE_E)

typedef __attribute__((ext_vector_type(8))) short bf16x8;
typedef __attribute__((ext_vector_type(4))) float f32x4;

static __device__ __forceinline__ unsigned short f2bf(float f) {
    unsigned u = __float_as_uint(f);
    unsigned r = (u + 0x7FFFu + ((u >> 16) & 1u)) >> 16;   // RNE
    return (unsigned short)r;
}
static __device__ __forceinline__ float bflo(unsigned u) { return __uint_as_float(u << 16); }
static __device__ __forceinline__ float bfhi(unsigned u) { return __uint_as_float(u & 0xffff0000u); }

// ---------------- fused prep: x2bf (planes 2,3) | wprep | cursor/stat init ----------------
__global__ __launch_bounds__(256) void prep_kernel(
    const float* __restrict__ x, unsigned short* __restrict__ A1,
    const float* __restrict__ W1l, const float* __restrict__ W1r,
    const float* __restrict__ W2l, const float* __restrict__ W2r,
    unsigned short* __restrict__ BT1, unsigned short* __restrict__ BT2,
    int* __restrict__ gcur, float* __restrict__ sums)
{
    int blk = blockIdx.x, tid = threadIdx.x;
    if (blk < XB) {
        int idx = blk * 256 + tid;
        int n = idx >> 4, q = idx & 15;
        float4 v = ((const float4*)x)[idx];
        ushort4 o;
        o.x = f2bf(v.x); o.y = f2bf(v.y); o.z = f2bf(v.z); o.w = f2bf(v.w);
        int plane = 2 + (q >> 3);
        *(ushort4*)(A1 + (size_t)plane * NN * 32 + (size_t)n * 32 + (q & 7) * 4) = o;
    } else if (blk < XB + 64) {
        int idx = (blk - XB) * 256 + tid;
        int j = idx >> 7, k = idx & 127;
        float v1 = (k < 64) ? W1l[k * HID + j] : W1r[(k - 64) * HID + j];
        BT1[j * 128 + k] = f2bf(v1);
        float v2 = (j < 64) ? W2l[k * OUTD + j] : W2r[k * OUTD + (j - 64)];
        BT2[j * 128 + k] = f2bf(v2);
    } else {
        if (tid < NBK) gcur[tid] = tid * CAP;
        sums[tid] = 0.f;
        sums[tid + 256] = 0.f;
    }
}

// ---------------- phase A: bin edges into fixed-capacity bucket regions ----------------
__global__ __launch_bounds__(256) void binA_kernel(const int* __restrict__ src,
                                                   const int* __restrict__ dst,
                                                   int* __restrict__ gcur,
                                                   int2* __restrict__ pairs) {
    __shared__ int lcnt[NBK];
    __shared__ int lbase[NBK];
    int tid = threadIdx.x;
    int e0 = blockIdx.x * TILE_E;
    for (int i = tid; i < NBK; i += 256) lcnt[i] = 0;
    __syncthreads();
    int s[16], d[16], loc[16];
#pragma unroll
    for (int i = 0; i < 16; i++) {
        int e = e0 + i * 256 + tid;
        if (e < NE) {
            s[i] = __builtin_nontemporal_load(&src[e]);
            d[i] = __builtin_nontemporal_load(&dst[e]);
            loc[i] = atomicAdd(&lcnt[d[i] / BWID], 1);
        }
    }
    __syncthreads();
    for (int b = tid; b < NBK; b += 256)
        lbase[b] = atomicAdd(&gcur[b], lcnt[b]);
    __syncthreads();
#pragma unroll
    for (int i = 0; i < 16; i++) {
        int e = e0 + i * 256 + tid;
        if (e < NE)
            pairs[lbase[d[i] / BWID] + loc[i]] = make_int2(s[i], d[i]);
    }
}

// ---------------- phase B: per-bucket CSR build + perm scatter (LDS atomics) ----------
__global__ __launch_bounds__(256) void binB_kernel(const int2* __restrict__ pairs,
                                                   const int* __restrict__ gcur,
                                                   int* __restrict__ startp,
                                                   int* __restrict__ endp,
                                                   int* __restrict__ perm) {
    __shared__ int lcnt[BWID];
    __shared__ int tmp[256];
    __shared__ int lcur[BWID];
    int b = blockIdx.x, tid = threadIdx.x;
    int lo = b * CAP;
    int hi = gcur[b];
    int base = b * BWID;
    for (int i = tid; i < BWID; i += 256) lcnt[i] = 0;
    __syncthreads();
    for (int i = lo + tid; i < hi; i += 256)
        atomicAdd(&lcnt[pairs[i].y - base], 1);
    __syncthreads();
    int v = (tid < BWID) ? lcnt[tid] : 0;
    tmp[tid] = v;
    __syncthreads();
    for (int off = 1; off < 256; off <<= 1) {
        int t = (tid >= off) ? tmp[tid - off] : 0;
        __syncthreads();
        tmp[tid] += t;
        __syncthreads();
    }
    if (tid < BWID) {
        int s = lo + tmp[tid] - v;
        lcur[tid] = s;
        startp[base + tid] = s;
        endp[base + tid] = s + v;
    }
    __syncthreads();
    for (int i = lo + tid; i < hi; i += 256) {
        int2 p = pairs[i];
        int pos = atomicAdd(&lcur[p.y - base], 1);
        perm[pos] = p.x;
    }
}

// ---------------- sliced gather-aggregate: one wave per node, one 32-col plane --------
// 16 edge-groups x 4 lanes x 16B. MODE 0: bf16 mean -> outb plane; MODE 1: outf += mean.
template<int MODE>
__global__ __launch_bounds__(256) void agg_gather_s(
    const unsigned short* __restrict__ plane,
    const int* __restrict__ startp, const int* __restrict__ endp,
    const int* __restrict__ perm,
    unsigned short* __restrict__ outb, float* __restrict__ outf)
{
    int wave = (blockIdx.x * blockDim.x + threadIdx.x) >> 6;
    if (wave >= NN) return;
    int lane = threadIdx.x & 63;
    int g = lane >> 2;        // 16 edge groups
    int q = lane & 3;         // 4 x 16B per row-slice
    int rs = startp[wave];
    int re = endp[wave];
    float acc[8];
#pragma unroll
    for (int t = 0; t < 8; t++) acc[t] = 0.f;
    for (int i = rs + g; i < re; i += 16) {
        int s = perm[i];
        uint4 v = *(const uint4*)(plane + (size_t)s * 32 + q * 8);
        acc[0] += bflo(v.x); acc[1] += bfhi(v.x);
        acc[2] += bflo(v.y); acc[3] += bfhi(v.y);
        acc[4] += bflo(v.z); acc[5] += bfhi(v.z);
        acc[6] += bflo(v.w); acc[7] += bfhi(v.w);
    }
#pragma unroll
    for (int t = 0; t < 8; t++) {
        acc[t] += __shfl_xor(acc[t], 4, 64);
        acc[t] += __shfl_xor(acc[t], 8, 64);
        acc[t] += __shfl_xor(acc[t], 16, 64);
        acc[t] += __shfl_xor(acc[t], 32, 64);
    }
    if (g == 0) {
        int cnt = re - rs;
        float inv = (cnt > 0) ? (1.0f / (float)cnt) : 0.f;
        if (MODE == 0) {
            uint4 o;
            o.x = (unsigned)f2bf(acc[0] * inv) | ((unsigned)f2bf(acc[1] * inv) << 16);
            o.y = (unsigned)f2bf(acc[2] * inv) | ((unsigned)f2bf(acc[3] * inv) << 16);
            o.z = (unsigned)f2bf(acc[4] * inv) | ((unsigned)f2bf(acc[5] * inv) << 16);
            o.w = (unsigned)f2bf(acc[6] * inv) | ((unsigned)f2bf(acc[7] * inv) << 16);
            *(uint4*)(outb + (size_t)wave * 32 + q * 8) = o;
        } else {
            float4* op = (float4*)(outf + (size_t)wave * 64 + q * 8);
            float4 o0 = op[0], o1 = op[1];
            o0.x += acc[0] * inv; o0.y += acc[1] * inv;
            o0.z += acc[2] * inv; o0.w += acc[3] * inv;
            o1.x += acc[4] * inv; o1.y += acc[5] * inv;
            o1.z += acc[6] * inv; o1.w += acc[7] * inv;
            op[0] = o0; op[1] = o1;
        }
    }
}

// ---------------- MFMA conv: B in registers, multi-tile per wave, A prefetch -------
// IS1: A in 4 planes of NN*32 (plane ks); bf16 store + BN stats.
// !IS1: A flat NN*128; p -> 2 planes at outb; self+b2 -> outf.
template<bool IS1>
__global__ __launch_bounds__(256) void conv_mfma_kernel(
    const unsigned short* __restrict__ A, const unsigned short* __restrict__ BT,
    const float* __restrict__ bias,
    unsigned short* __restrict__ outb, float* __restrict__ outf,
    float* __restrict__ sums, float* __restrict__ sumsq)
{
    __shared__ float red_s[4][128];
    __shared__ float red_q[4][128];
    int tid = threadIdx.x;
    int wid = tid >> 6, lane = tid & 63;
    int m = lane & 15, ko = lane >> 4;
    int gw = blockIdx.x * 4 + wid;
    int jh = gw & 1;
    int tstride = (gridDim.x * 4) >> 1;
    const int tiles = NN / 16;
    bf16x8 b[4][4];
    const unsigned short* bbase = BT + (size_t)(jh * 64 + m) * 128 + ko * 8;
#pragma unroll
    for (int jg = 0; jg < 4; jg++)
#pragma unroll
        for (int ks = 0; ks < 4; ks++)
            b[jg][ks] = *(const bf16x8*)(bbase + jg * 16 * 128 + ks * 32);
    float bj[4];
#pragma unroll
    for (int jg = 0; jg < 4; jg++)
        bj[jg] = IS1 ? bias[jh * 64 + jg * 16 + m] : (jh ? bias[jg * 16 + m] : 0.f);
    float s_sum[4] = {0.f, 0.f, 0.f, 0.f}, s_sq[4] = {0.f, 0.f, 0.f, 0.f};
    int tile = gw >> 1;
    bf16x8 a[4];
    if (tile < tiles) {
        int n = tile * 16 + m;
#pragma unroll
        for (int ks = 0; ks < 4; ks++)
            a[ks] = IS1 ? *(const bf16x8*)(A + (size_t)ks * NN * 32 + (size_t)n * 32 + ko * 8)
                        : *(const bf16x8*)(A + (size_t)n * 128 + ks * 32 + ko * 8);
    }
    while (tile < tiles) {
        int nxt = tile + tstride;
        bf16x8 an[4];
        if (nxt < tiles) {
            int n = nxt * 16 + m;
#pragma unroll
            for (int ks = 0; ks < 4; ks++)
                an[ks] = IS1 ? *(const bf16x8*)(A + (size_t)ks * NN * 32 + (size_t)n * 32 + ko * 8)
                             : *(const bf16x8*)(A + (size_t)n * 128 + ks * 32 + ko * 8);
        }
        int n0 = tile * 16;
#pragma unroll
        for (int jg = 0; jg < 4; jg++) {
            f32x4 acc = {0.f, 0.f, 0.f, 0.f};
#pragma unroll
            for (int ks = 0; ks < 4; ks++)
                acc = __builtin_amdgcn_mfma_f32_16x16x32_bf16(a[ks], b[jg][ks], acc, 0, 0, 0);
            int j = jh * 64 + jg * 16 + m;
#pragma unroll
            for (int r = 0; r < 4; r++) {
                int n = n0 + ko * 4 + r;
                float v = acc[r];
                if (IS1) {
                    v += bj[jg];
                    outb[(size_t)n * 128 + j] = f2bf(v);
                    s_sum[jg] += v;
                    s_sq[jg] += v * v;
                } else {
                    if (jh == 0)
                        outb[(size_t)(j >> 5) * NN * 32 + (size_t)n * 32 + (j & 31)] = f2bf(v);
                    else
                        outf[(size_t)n * 64 + (j - 64)] = v + bj[jg];
                }
            }
        }
#pragma unroll
        for (int ks = 0; ks < 4; ks++) a[ks] = an[ks];
        tile = nxt;
    }
    if (IS1) {
        for (int i = tid; i < 512; i += 256) {
            ((float*)red_s)[i] = 0.f;
            ((float*)red_q)[i] = 0.f;
        }
        __syncthreads();
#pragma unroll
        for (int jg = 0; jg < 4; jg++) {
            float v = s_sum[jg];
            v += __shfl_xor(v, 16, 64);
            v += __shfl_xor(v, 32, 64);
            float w = s_sq[jg];
            w += __shfl_xor(w, 16, 64);
            w += __shfl_xor(w, 32, 64);
            if (lane < 16) {
                red_s[wid][jh * 64 + jg * 16 + lane] = v;
                red_q[wid][jh * 64 + jg * 16 + lane] = w;
            }
        }
        __syncthreads();
        if (tid < 128) {
            float v = red_s[0][tid] + red_s[1][tid] + red_s[2][tid] + red_s[3][tid];
            atomicAdd(&sums[tid], v);
        } else {
            int j = tid - 128;
            float v = red_q[0][j] + red_q[1][j] + red_q[2][j] + red_q[3][j];
            atomicAdd(&sumsq[j], v);
        }
    }
}

// ---------------- BN stats -> scale/shift ----------------
__global__ void bnstat_kernel(const float* __restrict__ sums, const float* __restrict__ sumsq,
                              const float* __restrict__ gamma, const float* __restrict__ beta,
                              float* __restrict__ scale, float* __restrict__ shift) {
    int c = threadIdx.x;
    if (c < HID) {
        float inv_n = 1.0f / (float)NN;
        float mu = sums[c] * inv_n;
        float var = sumsq[c] * inv_n - mu * mu;
        float s = gamma[c] * rsqrtf(var + 1e-5f);
        scale[c] = s;
        shift[c] = beta[c] - mu * s;
    }
}

// ---------------- bn+relu apply: h = relu(bn(hpreb)) bf16 -> A1 flat ----------------
__global__ void bnapply_kernel(const unsigned short* __restrict__ hpreb,
                               const float* __restrict__ scale, const float* __restrict__ shift,
                               unsigned short* __restrict__ A1) {
    int idx = blockIdx.x * 256 + threadIdx.x;
    if (idx >= NN * 16) return;
    int q = idx & 15;
    int j0 = q * 8;
    uint4 v = ((const uint4*)hpreb)[idx];
    float f[8];
    f[0] = bflo(v.x); f[1] = bfhi(v.x);
    f[2] = bflo(v.y); f[3] = bfhi(v.y);
    f[4] = bflo(v.z); f[5] = bfhi(v.z);
    f[6] = bflo(v.w); f[7] = bfhi(v.w);
#pragma unroll
    for (int t = 0; t < 8; t++) {
        float h = f[t] * scale[j0 + t] + shift[j0 + t];
        f[t] = h > 0.f ? h : 0.f;
    }
    uint4 o;
    o.x = (unsigned)f2bf(f[0]) | ((unsigned)f2bf(f[1]) << 16);
    o.y = (unsigned)f2bf(f[2]) | ((unsigned)f2bf(f[3]) << 16);
    o.z = (unsigned)f2bf(f[4]) | ((unsigned)f2bf(f[5]) << 16);
    o.w = (unsigned)f2bf(f[6]) | ((unsigned)f2bf(f[7]) << 16);
    ((uint4*)A1)[idx] = o;
}

extern "C" void kernel_launch(void* const* d_in, const int* in_sizes, int n_in,
                              void* d_out, int out_size, void* d_ws, size_t ws_size,
                              hipStream_t stream) {
    const float* x     = (const float*)d_in[0];
    const int*   ei    = (const int*)d_in[1];
    const float* W1l   = (const float*)d_in[2];
    const float* b1    = (const float*)d_in[3];
    const float* W1r   = (const float*)d_in[4];
    const float* gamma = (const float*)d_in[5];
    const float* beta  = (const float*)d_in[6];
    const float* W2l   = (const float*)d_in[7];
    const float* b2    = (const float*)d_in[8];
    const float* W2r   = (const float*)d_in[9];
    float* out = (float*)d_out;

    // workspace layout (~30.2 MB; pairs aliases hpreb)
    char* wsb = (char*)d_ws;
    int*   gcur   = (int*)wsb;                                  // 256
    float* sums   = (float*)(gcur + 256);                       // 128
    float* sumsq  = sums + 128;                                 // 128
    float* scale  = sums + 256;                                 // 128
    float* shift  = sums + 384;                                 // 128
    int*   startp = (int*)(sums + 512);                         // NN
    int*   endp   = startp + NN;                                // NN
    int*   perm   = endp + NN;                                  // NBK*CAP
    unsigned short* A1    = (unsigned short*)(perm + NBK * CAP); // NN*128 bf16 (4 planes / flat)
    unsigned short* hpreb = A1 + (size_t)NN * 128;              // NN*128 bf16; pb planes reuse
    unsigned short* BT1   = hpreb + (size_t)NN * 128;           // 128*128 bf16
    unsigned short* BT2   = BT1 + 128 * 128;                    // 128*128 bf16
    int2*  pairs  = (int2*)hpreb;                               // NBK*CAP int2 (dead before conv1)

    const int* srcp = ei;
    const int* dstp = ei + NE;

    const int GB = (NN * 64 + 255) / 256;   // one wave per node
    const int CB = 512;                     // conv grid
    const size_t PL = (size_t)NN * 32;      // plane stride (bf16 elems)

    prep_kernel<<<XB + 64 + 1, 256, 0, stream>>>(x, A1, W1l, W1r, W2l, W2r,
                                                 BT1, BT2, gcur, sums);
    binA_kernel<<<HB, 256, 0, stream>>>(srcp, dstp, gcur, pairs);
    binB_kernel<<<NBK, 256, 0, stream>>>(pairs, gcur, startp, endp, perm);

    // agg1: per slice s, gather x-plane (2+s) -> mean into plane s
    agg_gather_s<0><<<GB, 256, 0, stream>>>(A1 + 2 * PL, startp, endp, perm,
                                            A1, nullptr);
    agg_gather_s<0><<<GB, 256, 0, stream>>>(A1 + 3 * PL, startp, endp, perm,
                                            A1 + PL, nullptr);
    // conv1: hpre = [agg|x](planes) @ [W1l;W1r] + b1 ; bf16 + BN stats
    conv_mfma_kernel<true><<<CB, 256, 0, stream>>>(A1, BT1, b1, hpreb, nullptr, sums, sumsq);
    bnstat_kernel<<<1, 128, 0, stream>>>(sums, sumsq, gamma, beta, scale, shift);
    bnapply_kernel<<<XB, 256, 0, stream>>>(hpreb, scale, shift, A1);
    // conv2: [p(planes)|self] = A1 @ [W2l|W2r] ; p -> hpreb planes, self+b2 -> out
    conv_mfma_kernel<false><<<CB, 256, 0, stream>>>(A1, BT2, b2, hpreb, out, nullptr, nullptr);
    // agg2: per slice s, gather pb plane s -> out cols [s*32, s*32+32) += mean
    agg_gather_s<1><<<GB, 256, 0, stream>>>(hpreb, startp, endp, perm,
                                            nullptr, out);
    agg_gather_s<1><<<GB, 256, 0, stream>>>(hpreb + PL, startp, endp, perm,
                                            nullptr, out + 32);
}

// Round 15
// 201.788 us; speedup vs baseline: 1.1878x; 1.1878x over previous
//
#include <hip/hip_runtime.h>

#define NN 50000
#define NE 800000
#define HID 128
#define OUTD 64
#define NBK 200      // buckets (dst-partition)
#define BWID 250     // nodes per bucket
#define CAP 5120     // padded capacity per bucket (mean 4000, +17 sigma)
#define TILE_E 4096  // edges per binA block
#define XB 3125      // NN*16/256 exact
#define HB 196       // ceil(NE/TILE_E)

typedef __attribute__((ext_vector_type(8))) short bf16x8;
typedef __attribute__((ext_vector_type(4))) float f32x4;

static __device__ __forceinline__ unsigned short f2bf(float f) {
    unsigned u = __float_as_uint(f);
    unsigned r = (u + 0x7FFFu + ((u >> 16) & 1u)) >> 16;   // RNE
    return (unsigned short)r;
}
static __device__ __forceinline__ float bflo(unsigned u) { return __uint_as_float(u << 16); }
static __device__ __forceinline__ float bfhi(unsigned u) { return __uint_as_float(u & 0xffff0000u); }

// ---------------- fused prep: x2bf (A1 cols 64:128) | wprep | cursor/stat init --------
__global__ __launch_bounds__(256) void prep_kernel(
    const float* __restrict__ x, unsigned short* __restrict__ A1,
    const float* __restrict__ W1l, const float* __restrict__ W1r,
    const float* __restrict__ W2l, const float* __restrict__ W2r,
    unsigned short* __restrict__ BT1, unsigned short* __restrict__ BT2,
    int* __restrict__ gcur, float* __restrict__ sums)
{
    int blk = blockIdx.x, tid = threadIdx.x;
    if (blk < XB) {
        int idx = blk * 256 + tid;
        int n = idx >> 4, q = idx & 15;
        float4 v = ((const float4*)x)[idx];
        ushort4 o;
        o.x = f2bf(v.x); o.y = f2bf(v.y); o.z = f2bf(v.z); o.w = f2bf(v.w);
        *(ushort4*)(A1 + (size_t)n * 128 + 64 + q * 4) = o;
    } else if (blk < XB + 64) {
        int idx = (blk - XB) * 256 + tid;
        int j = idx >> 7, k = idx & 127;
        float v1 = (k < 64) ? W1l[k * HID + j] : W1r[(k - 64) * HID + j];
        BT1[j * 128 + k] = f2bf(v1);
        float v2 = (j < 64) ? W2l[k * OUTD + j] : W2r[k * OUTD + (j - 64)];
        BT2[j * 128 + k] = f2bf(v2);
    } else {
        if (tid < NBK) gcur[tid] = tid * CAP;
        sums[tid] = 0.f;
        sums[tid + 256] = 0.f;
    }
}

// ---------------- phase A: bin edges into fixed-capacity bucket regions ----------------
__global__ __launch_bounds__(256) void binA_kernel(const int* __restrict__ src,
                                                   const int* __restrict__ dst,
                                                   int* __restrict__ gcur,
                                                   int2* __restrict__ pairs) {
    __shared__ int lcnt[NBK];
    __shared__ int lbase[NBK];
    int tid = threadIdx.x;
    int e0 = blockIdx.x * TILE_E;
    for (int i = tid; i < NBK; i += 256) lcnt[i] = 0;
    __syncthreads();
    int s[16], d[16], loc[16];
#pragma unroll
    for (int i = 0; i < 16; i++) {
        int e = e0 + i * 256 + tid;
        if (e < NE) {
            s[i] = __builtin_nontemporal_load(&src[e]);
            d[i] = __builtin_nontemporal_load(&dst[e]);
            loc[i] = atomicAdd(&lcnt[d[i] / BWID], 1);
        }
    }
    __syncthreads();
    for (int b = tid; b < NBK; b += 256)
        lbase[b] = atomicAdd(&gcur[b], lcnt[b]);
    __syncthreads();
#pragma unroll
    for (int i = 0; i < 16; i++) {
        int e = e0 + i * 256 + tid;
        if (e < NE)
            pairs[lbase[d[i] / BWID] + loc[i]] = make_int2(s[i], d[i]);
    }
}

// ---------------- phase B: per-bucket CSR build + perm scatter (LDS atomics) ----------
__global__ __launch_bounds__(256) void binB_kernel(const int2* __restrict__ pairs,
                                                   const int* __restrict__ gcur,
                                                   int* __restrict__ startp,
                                                   int* __restrict__ endp,
                                                   int* __restrict__ perm) {
    __shared__ int lcnt[BWID];
    __shared__ int tmp[256];
    __shared__ int lcur[BWID];
    int b = blockIdx.x, tid = threadIdx.x;
    int lo = b * CAP;
    int hi = gcur[b];
    int base = b * BWID;
    for (int i = tid; i < BWID; i += 256) lcnt[i] = 0;
    __syncthreads();
    for (int i = lo + tid; i < hi; i += 256)
        atomicAdd(&lcnt[pairs[i].y - base], 1);
    __syncthreads();
    int v = (tid < BWID) ? lcnt[tid] : 0;
    tmp[tid] = v;
    __syncthreads();
    for (int off = 1; off < 256; off <<= 1) {
        int t = (tid >= off) ? tmp[tid - off] : 0;
        __syncthreads();
        tmp[tid] += t;
        __syncthreads();
    }
    if (tid < BWID) {
        int s = lo + tmp[tid] - v;
        lcur[tid] = s;
        startp[base + tid] = s;
        endp[base + tid] = s + v;
    }
    __syncthreads();
    for (int i = lo + tid; i < hi; i += 256) {
        int2 p = pairs[i];
        int pos = atomicAdd(&lcur[p.y - base], 1);
        perm[pos] = p.x;
    }
}

// ---------------- gather-aggregate over bf16 rows, one wave per node (full row) ------
// 2x unrolled. MODE 0: store bf16 mean into outb row; MODE 1: outf[n*64+c] += mean (fp32)
template<int MODE>
__global__ __launch_bounds__(256) void agg_gather_b(
    const unsigned short* __restrict__ feat, int fstride, int foff,
    const int* __restrict__ startp, const int* __restrict__ endp,
    const int* __restrict__ perm,
    unsigned short* __restrict__ outb, int ostride, int ooff,
    float* __restrict__ outf)
{
    int wave = (blockIdx.x * blockDim.x + threadIdx.x) >> 6;
    if (wave >= NN) return;
    int lane = threadIdx.x & 63;
    int g = lane >> 3;        // 8 edge groups
    int q = lane & 7;         // 8 bf16 per slot
    int rs = startp[wave];
    int re = endp[wave];
    float acc[8];
#pragma unroll
    for (int t = 0; t < 8; t++) acc[t] = 0.f;
    int i = rs + g;
    for (; i + 8 < re; i += 16) {
        int s0 = perm[i];
        int s1 = perm[i + 8];
        uint4 v0 = *(const uint4*)(feat + (size_t)s0 * fstride + foff + q * 8);
        uint4 v1 = *(const uint4*)(feat + (size_t)s1 * fstride + foff + q * 8);
        acc[0] += bflo(v0.x); acc[1] += bfhi(v0.x);
        acc[2] += bflo(v0.y); acc[3] += bfhi(v0.y);
        acc[4] += bflo(v0.z); acc[5] += bfhi(v0.z);
        acc[6] += bflo(v0.w); acc[7] += bfhi(v0.w);
        acc[0] += bflo(v1.x); acc[1] += bfhi(v1.x);
        acc[2] += bflo(v1.y); acc[3] += bfhi(v1.y);
        acc[4] += bflo(v1.z); acc[5] += bfhi(v1.z);
        acc[6] += bflo(v1.w); acc[7] += bfhi(v1.w);
    }
    if (i < re) {
        int s0 = perm[i];
        uint4 v0 = *(const uint4*)(feat + (size_t)s0 * fstride + foff + q * 8);
        acc[0] += bflo(v0.x); acc[1] += bfhi(v0.x);
        acc[2] += bflo(v0.y); acc[3] += bfhi(v0.y);
        acc[4] += bflo(v0.z); acc[5] += bfhi(v0.z);
        acc[6] += bflo(v0.w); acc[7] += bfhi(v0.w);
    }
#pragma unroll
    for (int t = 0; t < 8; t++) {
        acc[t] += __shfl_xor(acc[t], 8, 64);
        acc[t] += __shfl_xor(acc[t], 16, 64);
        acc[t] += __shfl_xor(acc[t], 32, 64);
    }
    if (g == 0) {
        int cnt = re - rs;
        float inv = (cnt > 0) ? (1.0f / (float)cnt) : 0.f;
        if (MODE == 0) {
            uint4 o;
            o.x = (unsigned)f2bf(acc[0] * inv) | ((unsigned)f2bf(acc[1] * inv) << 16);
            o.y = (unsigned)f2bf(acc[2] * inv) | ((unsigned)f2bf(acc[3] * inv) << 16);
            o.z = (unsigned)f2bf(acc[4] * inv) | ((unsigned)f2bf(acc[5] * inv) << 16);
            o.w = (unsigned)f2bf(acc[6] * inv) | ((unsigned)f2bf(acc[7] * inv) << 16);
            *(uint4*)(outb + (size_t)wave * ostride + ooff + q * 8) = o;
        } else {
            float4* op = (float4*)(outf + (size_t)wave * 64 + q * 8);
            float4 o0 = op[0], o1 = op[1];
            o0.x += acc[0] * inv; o0.y += acc[1] * inv;
            o0.z += acc[2] * inv; o0.w += acc[3] * inv;
            o1.x += acc[4] * inv; o1.y += acc[5] * inv;
            o1.z += acc[6] * inv; o1.w += acc[7] * inv;
            op[0] = o0; op[1] = o1;
        }
    }
}

// ---------------- MFMA conv: B in registers, multi-tile per wave, A prefetch -------
template<bool IS1>
__global__ __launch_bounds__(256) void conv_mfma_kernel(
    const unsigned short* __restrict__ A, const unsigned short* __restrict__ BT,
    const float* __restrict__ bias,
    unsigned short* __restrict__ outb, float* __restrict__ outf,
    float* __restrict__ sums, float* __restrict__ sumsq)
{
    __shared__ float red_s[4][128];
    __shared__ float red_q[4][128];
    int tid = threadIdx.x;
    int wid = tid >> 6, lane = tid & 63;
    int m = lane & 15, ko = lane >> 4;
    int gw = blockIdx.x * 4 + wid;
    int jh = gw & 1;
    int tstride = (gridDim.x * 4) >> 1;
    const int tiles = NN / 16;
    bf16x8 b[4][4];
    const unsigned short* bbase = BT + (size_t)(jh * 64 + m) * 128 + ko * 8;
#pragma unroll
    for (int jg = 0; jg < 4; jg++)
#pragma unroll
        for (int ks = 0; ks < 4; ks++)
            b[jg][ks] = *(const bf16x8*)(bbase + jg * 16 * 128 + ks * 32);
    float bj[4];
#pragma unroll
    for (int jg = 0; jg < 4; jg++)
        bj[jg] = IS1 ? bias[jh * 64 + jg * 16 + m] : (jh ? bias[jg * 16 + m] : 0.f);
    float s_sum[4] = {0.f, 0.f, 0.f, 0.f}, s_sq[4] = {0.f, 0.f, 0.f, 0.f};
    int tile = gw >> 1;
    bf16x8 a[4];
    if (tile < tiles) {
        const unsigned short* arow = A + (size_t)(tile * 16 + m) * 128 + ko * 8;
#pragma unroll
        for (int ks = 0; ks < 4; ks++) a[ks] = *(const bf16x8*)(arow + ks * 32);
    }
    while (tile < tiles) {
        int nxt = tile + tstride;
        bf16x8 an[4];
        if (nxt < tiles) {
            const unsigned short* arow = A + (size_t)(nxt * 16 + m) * 128 + ko * 8;
#pragma unroll
            for (int ks = 0; ks < 4; ks++) an[ks] = *(const bf16x8*)(arow + ks * 32);
        }
        int n0 = tile * 16;
#pragma unroll
        for (int jg = 0; jg < 4; jg++) {
            f32x4 acc = {0.f, 0.f, 0.f, 0.f};
#pragma unroll
            for (int ks = 0; ks < 4; ks++)
                acc = __builtin_amdgcn_mfma_f32_16x16x32_bf16(a[ks], b[jg][ks], acc, 0, 0, 0);
            int j = jh * 64 + jg * 16 + m;
#pragma unroll
            for (int r = 0; r < 4; r++) {
                int n = n0 + ko * 4 + r;
                float v = acc[r];
                if (IS1) {
                    v += bj[jg];
                    outb[(size_t)n * 128 + j] = f2bf(v);
                    s_sum[jg] += v;
                    s_sq[jg] += v * v;
                } else {
                    if (jh == 0) outb[(size_t)n * 64 + j] = f2bf(v);
                    else         outf[(size_t)n * 64 + (j - 64)] = v + bj[jg];
                }
            }
        }
#pragma unroll
        for (int ks = 0; ks < 4; ks++) a[ks] = an[ks];
        tile = nxt;
    }
    if (IS1) {
        for (int i = tid; i < 512; i += 256) {
            ((float*)red_s)[i] = 0.f;
            ((float*)red_q)[i] = 0.f;
        }
        __syncthreads();
#pragma unroll
        for (int jg = 0; jg < 4; jg++) {
            float v = s_sum[jg];
            v += __shfl_xor(v, 16, 64);
            v += __shfl_xor(v, 32, 64);
            float w = s_sq[jg];
            w += __shfl_xor(w, 16, 64);
            w += __shfl_xor(w, 32, 64);
            if (lane < 16) {
                red_s[wid][jh * 64 + jg * 16 + lane] = v;
                red_q[wid][jh * 64 + jg * 16 + lane] = w;
            }
        }
        __syncthreads();
        if (tid < 128) {
            float v = red_s[0][tid] + red_s[1][tid] + red_s[2][tid] + red_s[3][tid];
            atomicAdd(&sums[tid], v);
        } else {
            int j = tid - 128;
            float v = red_q[0][j] + red_q[1][j] + red_q[2][j] + red_q[3][j];
            atomicAdd(&sumsq[j], v);
        }
    }
}

// ---------------- BN stats -> scale/shift ----------------
__global__ void bnstat_kernel(const float* __restrict__ sums, const float* __restrict__ sumsq,
                              const float* __restrict__ gamma, const float* __restrict__ beta,
                              float* __restrict__ scale, float* __restrict__ shift) {
    int c = threadIdx.x;
    if (c < HID) {
        float inv_n = 1.0f / (float)NN;
        float mu = sums[c] * inv_n;
        float var = sumsq[c] * inv_n - mu * mu;
        float s = gamma[c] * rsqrtf(var + 1e-5f);
        scale[c] = s;
        shift[c] = beta[c] - mu * s;
    }
}

// ---------------- bn+relu apply: h = relu(bn(hpreb)) bf16 -> A1 ----------------
__global__ void bnapply_kernel(const unsigned short* __restrict__ hpreb,
                               const float* __restrict__ scale, const float* __restrict__ shift,
                               unsigned short* __restrict__ A1) {
    int idx = blockIdx.x * 256 + threadIdx.x;
    if (idx >= NN * 16) return;
    int q = idx & 15;
    int j0 = q * 8;
    uint4 v = ((const uint4*)hpreb)[idx];
    float f[8];
    f[0] = bflo(v.x); f[1] = bfhi(v.x);
    f[2] = bflo(v.y); f[3] = bfhi(v.y);
    f[4] = bflo(v.z); f[5] = bfhi(v.z);
    f[6] = bflo(v.w); f[7] = bfhi(v.w);
#pragma unroll
    for (int t = 0; t < 8; t++) {
        float h = f[t] * scale[j0 + t] + shift[j0 + t];
        f[t] = h > 0.f ? h : 0.f;
    }
    uint4 o;
    o.x = (unsigned)f2bf(f[0]) | ((unsigned)f2bf(f[1]) << 16);
    o.y = (unsigned)f2bf(f[2]) | ((unsigned)f2bf(f[3]) << 16);
    o.z = (unsigned)f2bf(f[4]) | ((unsigned)f2bf(f[5]) << 16);
    o.w = (unsigned)f2bf(f[6]) | ((unsigned)f2bf(f[7]) << 16);
    ((uint4*)A1)[idx] = o;
}

extern "C" void kernel_launch(void* const* d_in, const int* in_sizes, int n_in,
                              void* d_out, int out_size, void* d_ws, size_t ws_size,
                              hipStream_t stream) {
    const float* x     = (const float*)d_in[0];
    const int*   ei    = (const int*)d_in[1];
    const float* W1l   = (const float*)d_in[2];
    const float* b1    = (const float*)d_in[3];
    const float* W1r   = (const float*)d_in[4];
    const float* gamma = (const float*)d_in[5];
    const float* beta  = (const float*)d_in[6];
    const float* W2l   = (const float*)d_in[7];
    const float* b2    = (const float*)d_in[8];
    const float* W2r   = (const float*)d_in[9];
    float* out = (float*)d_out;

    // workspace layout (~30.3 MB; pairs aliases hpreb)
    char* wsb = (char*)d_ws;
    int*   gcur   = (int*)wsb;                                   // 256
    float* sums   = (float*)(gcur + 256);                        // 128
    float* sumsq  = sums + 128;                                  // 128
    float* scale  = sums + 256;                                  // 128
    float* shift  = sums + 384;                                  // 128
    int*   startp = (int*)(sums + 512);                          // NN
    int*   endp   = startp + NN;                                 // NN
    int*   perm   = endp + NN;                                   // NBK*CAP
    unsigned short* A1    = (unsigned short*)(perm + NBK * CAP); // NN*128 bf16
    unsigned short* hpreb = A1 + (size_t)NN * 128;               // NN*128 bf16; reused as pb
    unsigned short* BT1   = hpreb + (size_t)NN * 128;            // 128*128 bf16
    unsigned short* BT2   = BT1 + 128 * 128;                     // 128*128 bf16
    int2*  pairs  = (int2*)hpreb;                                // NBK*CAP int2 (dead before conv1)

    const int* srcp = ei;
    const int* dstp = ei + NE;

    const int GB = (NN * 64 + 255) / 256;   // one wave per node
    const int CB = 512;                     // conv grid

    prep_kernel<<<XB + 64 + 1, 256, 0, stream>>>(x, A1, W1l, W1r, W2l, W2r,
                                                 BT1, BT2, gcur, sums);
    binA_kernel<<<HB, 256, 0, stream>>>(srcp, dstp, gcur, pairs);
    binB_kernel<<<NBK, 256, 0, stream>>>(pairs, gcur, startp, endp, perm);

    // agg1: gather A1 x-half (cols 64:128) -> bf16 mean into A1 cols 0:64
    agg_gather_b<0><<<GB, 256, 0, stream>>>(A1, 128, 64, startp, endp, perm,
                                            A1, 128, 0, nullptr);
    // conv1: hpre = A1 @ [W1l;W1r] + b1 ; bf16 store + fp32 BN stats
    conv_mfma_kernel<true><<<CB, 256, 0, stream>>>(A1, BT1, b1, hpreb, nullptr, sums, sumsq);
    bnstat_kernel<<<1, 128, 0, stream>>>(sums, sumsq, gamma, beta, scale, shift);
    // h = relu(bn(hpreb)) -> A1
    bnapply_kernel<<<XB, 256, 0, stream>>>(hpreb, scale, shift, A1);
    // conv2: [p | self] = A1 @ [W2l|W2r] ; p bf16 -> hpreb(=pb), self+b2 -> out
    conv_mfma_kernel<false><<<CB, 256, 0, stream>>>(A1, BT2, b2, hpreb, out, nullptr, nullptr);
    // agg2: gather pb rows -> out += mean
    agg_gather_b<1><<<GB, 256, 0, stream>>>(hpreb, 64, 0, startp, endp, perm,
                                            nullptr, 0, 0, out);
}

// Round 16
// 201.157 us; speedup vs baseline: 1.1915x; 1.0031x over previous
//
#include <hip/hip_runtime.h>

#define NN 50000
#define NE 800000
#define HID 128
#define OUTD 64
#define NBK 200      // buckets (dst-partition)
#define BWID 250     // nodes per bucket
#define CAP 5120     // padded capacity per bucket (mean 4000, +17 sigma)
#define TILE_E 4096  // edges per binA block
#define XB 3125      // NN*16/256 exact
#define HB 196       // ceil(NE/TILE_E)

typedef __attribute__((ext_vector_type(8))) short bf16x8;
typedef __attribute__((ext_vector_type(4))) float f32x4;

static __device__ __forceinline__ unsigned short f2bf(float f) {
    unsigned u = __float_as_uint(f);
    unsigned r = (u + 0x7FFFu + ((u >> 16) & 1u)) >> 16;   // RNE
    return (unsigned short)r;
}
static __device__ __forceinline__ float bflo(unsigned u) { return __uint_as_float(u << 16); }
static __device__ __forceinline__ float bfhi(unsigned u) { return __uint_as_float(u & 0xffff0000u); }

// ---------------- fused prep: x2bf (A1 cols 64:128) | wprep | cursor/stat init --------
__global__ __launch_bounds__(256) void prep_kernel(
    const float* __restrict__ x, unsigned short* __restrict__ A1,
    const float* __restrict__ W1l, const float* __restrict__ W1r,
    const float* __restrict__ W2l, const float* __restrict__ W2r,
    unsigned short* __restrict__ BT1, unsigned short* __restrict__ BT2,
    int* __restrict__ gcur, float* __restrict__ sums)
{
    int blk = blockIdx.x, tid = threadIdx.x;
    if (blk < XB) {
        int idx = blk * 256 + tid;
        int n = idx >> 4, q = idx & 15;
        float4 v = ((const float4*)x)[idx];
        ushort4 o;
        o.x = f2bf(v.x); o.y = f2bf(v.y); o.z = f2bf(v.z); o.w = f2bf(v.w);
        *(ushort4*)(A1 + (size_t)n * 128 + 64 + q * 4) = o;
    } else if (blk < XB + 64) {
        int idx = (blk - XB) * 256 + tid;
        int j = idx >> 7, k = idx & 127;
        float v1 = (k < 64) ? W1l[k * HID + j] : W1r[(k - 64) * HID + j];
        BT1[j * 128 + k] = f2bf(v1);
        float v2 = (j < 64) ? W2l[k * OUTD + j] : W2r[k * OUTD + (j - 64)];
        BT2[j * 128 + k] = f2bf(v2);
    } else {
        if (tid < NBK) gcur[tid] = tid * CAP;
        sums[tid] = 0.f;                    // zeroes sums[128] + sumsq[128]
    }
}

// ---------------- phase A: bin edges into fixed-capacity bucket regions ----------------
__global__ __launch_bounds__(256) void binA_kernel(const int* __restrict__ src,
                                                   const int* __restrict__ dst,
                                                   int* __restrict__ gcur,
                                                   int2* __restrict__ pairs) {
    __shared__ int lcnt[NBK];
    __shared__ int lbase[NBK];
    int tid = threadIdx.x;
    int e0 = blockIdx.x * TILE_E;
    for (int i = tid; i < NBK; i += 256) lcnt[i] = 0;
    __syncthreads();
    int s[16], d[16], loc[16];
#pragma unroll
    for (int i = 0; i < 16; i++) {
        int e = e0 + i * 256 + tid;
        if (e < NE) {
            s[i] = __builtin_nontemporal_load(&src[e]);
            d[i] = __builtin_nontemporal_load(&dst[e]);
            loc[i] = atomicAdd(&lcnt[d[i] / BWID], 1);
        }
    }
    __syncthreads();
    for (int b = tid; b < NBK; b += 256)
        lbase[b] = atomicAdd(&gcur[b], lcnt[b]);
    __syncthreads();
#pragma unroll
    for (int i = 0; i < 16; i++) {
        int e = e0 + i * 256 + tid;
        if (e < NE)
            pairs[lbase[d[i] / BWID] + loc[i]] = make_int2(s[i], d[i]);
    }
}

// ---------------- phase B: per-bucket CSR build + perm scatter (LDS atomics) ----------
__global__ __launch_bounds__(256) void binB_kernel(const int2* __restrict__ pairs,
                                                   const int* __restrict__ gcur,
                                                   int* __restrict__ startp,
                                                   int* __restrict__ endp,
                                                   int* __restrict__ perm) {
    __shared__ int lcnt[BWID];
    __shared__ int tmp[256];
    __shared__ int lcur[BWID];
    int b = blockIdx.x, tid = threadIdx.x;
    int lo = b * CAP;
    int hi = gcur[b];
    int base = b * BWID;
    for (int i = tid; i < BWID; i += 256) lcnt[i] = 0;
    __syncthreads();
    for (int i = lo + tid; i < hi; i += 256)
        atomicAdd(&lcnt[pairs[i].y - base], 1);
    __syncthreads();
    int v = (tid < BWID) ? lcnt[tid] : 0;
    tmp[tid] = v;
    __syncthreads();
    for (int off = 1; off < 256; off <<= 1) {
        int t = (tid >= off) ? tmp[tid - off] : 0;
        __syncthreads();
        tmp[tid] += t;
        __syncthreads();
    }
    if (tid < BWID) {
        int s = lo + tmp[tid] - v;
        lcur[tid] = s;
        startp[base + tid] = s;
        endp[base + tid] = s + v;
    }
    __syncthreads();
    for (int i = lo + tid; i < hi; i += 256) {
        int2 p = pairs[i];
        int pos = atomicAdd(&lcur[p.y - base], 1);
        perm[pos] = p.x;
    }
}

// ---------------- gather-aggregate over bf16 rows, one wave per node (full row) ------
// 2x unrolled. MODE 0: store bf16 mean into outb row; MODE 1: outf[n*64+c] += mean (fp32)
template<int MODE>
__global__ __launch_bounds__(256) void agg_gather_b(
    const unsigned short* __restrict__ feat, int fstride, int foff,
    const int* __restrict__ startp, const int* __restrict__ endp,
    const int* __restrict__ perm,
    unsigned short* __restrict__ outb, int ostride, int ooff,
    float* __restrict__ outf)
{
    int wave = (blockIdx.x * blockDim.x + threadIdx.x) >> 6;
    if (wave >= NN) return;
    int lane = threadIdx.x & 63;
    int g = lane >> 3;        // 8 edge groups
    int q = lane & 7;         // 8 bf16 per slot
    int rs = startp[wave];
    int re = endp[wave];
    float acc[8];
#pragma unroll
    for (int t = 0; t < 8; t++) acc[t] = 0.f;
    int i = rs + g;
    for (; i + 8 < re; i += 16) {
        int s0 = perm[i];
        int s1 = perm[i + 8];
        uint4 v0 = *(const uint4*)(feat + (size_t)s0 * fstride + foff + q * 8);
        uint4 v1 = *(const uint4*)(feat + (size_t)s1 * fstride + foff + q * 8);
        acc[0] += bflo(v0.x); acc[1] += bfhi(v0.x);
        acc[2] += bflo(v0.y); acc[3] += bfhi(v0.y);
        acc[4] += bflo(v0.z); acc[5] += bfhi(v0.z);
        acc[6] += bflo(v0.w); acc[7] += bfhi(v0.w);
        acc[0] += bflo(v1.x); acc[1] += bfhi(v1.x);
        acc[2] += bflo(v1.y); acc[3] += bfhi(v1.y);
        acc[4] += bflo(v1.z); acc[5] += bfhi(v1.z);
        acc[6] += bflo(v1.w); acc[7] += bfhi(v1.w);
    }
    if (i < re) {
        int s0 = perm[i];
        uint4 v0 = *(const uint4*)(feat + (size_t)s0 * fstride + foff + q * 8);
        acc[0] += bflo(v0.x); acc[1] += bfhi(v0.x);
        acc[2] += bflo(v0.y); acc[3] += bfhi(v0.y);
        acc[4] += bflo(v0.z); acc[5] += bfhi(v0.z);
        acc[6] += bflo(v0.w); acc[7] += bfhi(v0.w);
    }
#pragma unroll
    for (int t = 0; t < 8; t++) {
        acc[t] += __shfl_xor(acc[t], 8, 64);
        acc[t] += __shfl_xor(acc[t], 16, 64);
        acc[t] += __shfl_xor(acc[t], 32, 64);
    }
    if (g == 0) {
        int cnt = re - rs;
        float inv = (cnt > 0) ? (1.0f / (float)cnt) : 0.f;
        if (MODE == 0) {
            uint4 o;
            o.x = (unsigned)f2bf(acc[0] * inv) | ((unsigned)f2bf(acc[1] * inv) << 16);
            o.y = (unsigned)f2bf(acc[2] * inv) | ((unsigned)f2bf(acc[3] * inv) << 16);
            o.z = (unsigned)f2bf(acc[4] * inv) | ((unsigned)f2bf(acc[5] * inv) << 16);
            o.w = (unsigned)f2bf(acc[6] * inv) | ((unsigned)f2bf(acc[7] * inv) << 16);
            *(uint4*)(outb + (size_t)wave * ostride + ooff + q * 8) = o;
        } else {
            float4* op = (float4*)(outf + (size_t)wave * 64 + q * 8);
            float4 o0 = op[0], o1 = op[1];
            o0.x += acc[0] * inv; o0.y += acc[1] * inv;
            o0.z += acc[2] * inv; o0.w += acc[3] * inv;
            o1.x += acc[4] * inv; o1.y += acc[5] * inv;
            o1.z += acc[6] * inv; o1.w += acc[7] * inv;
            op[0] = o0; op[1] = o1;
        }
    }
}

// ---------------- MFMA conv v4: weights as A-operand -> D = C^T -> packed stores ------
// Lane holds col n = lane&15 (node), rows j_local = ko*4+r (4 consecutive j!).
// IS1: +b1, 8B bf16 stores to outb[n*128+j..], per-(jg,r) BN stats.
// !IS1: jh=0 -> 8B bf16 pb[n*64+j..]; jh=1 -> 16B f32 out[n*64+(j-64)..] + b2.
template<bool IS1>
__global__ __launch_bounds__(256) void conv_mfma_kernel(
    const unsigned short* __restrict__ A, const unsigned short* __restrict__ BT,
    const float* __restrict__ bias,
    unsigned short* __restrict__ outb, float* __restrict__ outf,
    float* __restrict__ sums, float* __restrict__ sumsq)
{
    __shared__ float red_s[4][128];
    __shared__ float red_q[4][128];
    int tid = threadIdx.x;
    int wid = tid >> 6, lane = tid & 63;
    int nl = lane & 15, ko = lane >> 4;
    int gw = blockIdx.x * 4 + wid;
    int jh = gw & 1;
    int tstride = (gridDim.x * 4) >> 1;
    const int tiles = NN / 16;             // 3125 exact (no tail)
    // weight frags (A-operand): lane nl = weight row j within each jg block
    bf16x8 b[4][4];
    const unsigned short* bbase = BT + (size_t)(jh * 64 + nl) * 128 + ko * 8;
#pragma unroll
    for (int jg = 0; jg < 4; jg++)
#pragma unroll
        for (int ks = 0; ks < 4; ks++)
            b[jg][ks] = *(const bf16x8*)(bbase + jg * 16 * 128 + ks * 32);
    // bias per (jg,r): j = jh*64 + jg*16 + ko*4 + r
    float4 bias4[4];
#pragma unroll
    for (int jg = 0; jg < 4; jg++) {
        if (IS1)        bias4[jg] = *(const float4*)(bias + jh * 64 + jg * 16 + ko * 4);
        else if (jh)    bias4[jg] = *(const float4*)(bias + jg * 16 + ko * 4);
        else            bias4[jg] = make_float4(0.f, 0.f, 0.f, 0.f);
    }
    float s_sum[16], s_sq[16];
#pragma unroll
    for (int t = 0; t < 16; t++) { s_sum[t] = 0.f; s_sq[t] = 0.f; }
    int tile = gw >> 1;
    bf16x8 a[4];
    if (tile < tiles) {
        const unsigned short* arow = A + (size_t)(tile * 16 + nl) * 128 + ko * 8;
#pragma unroll
        for (int ks = 0; ks < 4; ks++) a[ks] = *(const bf16x8*)(arow + ks * 32);
    }
    while (tile < tiles) {
        int nxt = tile + tstride;
        bf16x8 an[4];
        if (nxt < tiles) {
            const unsigned short* arow = A + (size_t)(nxt * 16 + nl) * 128 + ko * 8;
#pragma unroll
            for (int ks = 0; ks < 4; ks++) an[ks] = *(const bf16x8*)(arow + ks * 32);
        }
        int n_g = tile * 16 + nl;          // node this lane stores
#pragma unroll
        for (int jg = 0; jg < 4; jg++) {
            f32x4 acc = {0.f, 0.f, 0.f, 0.f};
#pragma unroll
            for (int ks = 0; ks < 4; ks++)
                acc = __builtin_amdgcn_mfma_f32_16x16x32_bf16(b[jg][ks], a[ks], acc, 0, 0, 0);
            float v0 = acc[0] + bias4[jg].x;
            float v1 = acc[1] + bias4[jg].y;
            float v2 = acc[2] + bias4[jg].z;
            float v3 = acc[3] + bias4[jg].w;
            if (IS1) {
                s_sum[jg * 4 + 0] += v0; s_sq[jg * 4 + 0] += v0 * v0;
                s_sum[jg * 4 + 1] += v1; s_sq[jg * 4 + 1] += v1 * v1;
                s_sum[jg * 4 + 2] += v2; s_sq[jg * 4 + 2] += v2 * v2;
                s_sum[jg * 4 + 3] += v3; s_sq[jg * 4 + 3] += v3 * v3;
                uint2 pk;
                pk.x = (unsigned)f2bf(v0) | ((unsigned)f2bf(v1) << 16);
                pk.y = (unsigned)f2bf(v2) | ((unsigned)f2bf(v3) << 16);
                *(uint2*)(outb + (size_t)n_g * 128 + jh * 64 + jg * 16 + ko * 4) = pk;
            } else {
                if (jh == 0) {
                    uint2 pk;
                    pk.x = (unsigned)f2bf(v0) | ((unsigned)f2bf(v1) << 16);
                    pk.y = (unsigned)f2bf(v2) | ((unsigned)f2bf(v3) << 16);
                    *(uint2*)(outb + (size_t)n_g * 64 + jg * 16 + ko * 4) = pk;
                } else {
                    float4 o = make_float4(v0, v1, v2, v3);
                    *(float4*)(outf + (size_t)n_g * 64 + jg * 16 + ko * 4) = o;
                }
            }
        }
#pragma unroll
        for (int ks = 0; ks < 4; ks++) a[ks] = an[ks];
        tile = nxt;
    }
    if (IS1) {
        for (int i = tid; i < 512; i += 256) {
            ((float*)red_s)[i] = 0.f;
            ((float*)red_q)[i] = 0.f;
        }
        __syncthreads();
#pragma unroll
        for (int jg = 0; jg < 4; jg++) {
#pragma unroll
            for (int r = 0; r < 4; r++) {
                float v = s_sum[jg * 4 + r];
                v += __shfl_xor(v, 1, 64);
                v += __shfl_xor(v, 2, 64);
                v += __shfl_xor(v, 4, 64);
                v += __shfl_xor(v, 8, 64);
                float w = s_sq[jg * 4 + r];
                w += __shfl_xor(w, 1, 64);
                w += __shfl_xor(w, 2, 64);
                w += __shfl_xor(w, 4, 64);
                w += __shfl_xor(w, 8, 64);
                if (nl == 0) {
                    red_s[wid][jh * 64 + jg * 16 + ko * 4 + r] = v;
                    red_q[wid][jh * 64 + jg * 16 + ko * 4 + r] = w;
                }
            }
        }
        __syncthreads();
        if (tid < 128) {
            float v = red_s[0][tid] + red_s[1][tid] + red_s[2][tid] + red_s[3][tid];
            atomicAdd(&sums[tid], v);
        } else {
            int j = tid - 128;
            float v = red_q[0][j] + red_q[1][j] + red_q[2][j] + red_q[3][j];
            atomicAdd(&sumsq[j], v);
        }
    }
}

// ---------------- bn stats + apply fused: h = relu(bn(hpreb)) bf16 -> A1 --------------
__global__ __launch_bounds__(256) void bnapply_kernel(
    const unsigned short* __restrict__ hpreb,
    const float* __restrict__ sums, const float* __restrict__ sumsq,
    const float* __restrict__ gamma, const float* __restrict__ beta,
    unsigned short* __restrict__ A1)
{
    __shared__ float sc[128], sh[128];
    int tid = threadIdx.x;
    if (tid < 128) {
        float inv_n = 1.0f / (float)NN;
        float mu = sums[tid] * inv_n;
        float var = sumsq[tid] * inv_n - mu * mu;
        float s = gamma[tid] * rsqrtf(var + 1e-5f);
        sc[tid] = s;
        sh[tid] = beta[tid] - mu * s;
    }
    __syncthreads();
    int idx = blockIdx.x * 256 + tid;
    if (idx >= NN * 16) return;
    int q = idx & 15;
    int j0 = q * 8;
    uint4 v = ((const uint4*)hpreb)[idx];
    float f[8];
    f[0] = bflo(v.x); f[1] = bfhi(v.x);
    f[2] = bflo(v.y); f[3] = bfhi(v.y);
    f[4] = bflo(v.z); f[5] = bfhi(v.z);
    f[6] = bflo(v.w); f[7] = bfhi(v.w);
#pragma unroll
    for (int t = 0; t < 8; t++) {
        float h = f[t] * sc[j0 + t] + sh[j0 + t];
        f[t] = h > 0.f ? h : 0.f;
    }
    uint4 o;
    o.x = (unsigned)f2bf(f[0]) | ((unsigned)f2bf(f[1]) << 16);
    o.y = (unsigned)f2bf(f[2]) | ((unsigned)f2bf(f[3]) << 16);
    o.z = (unsigned)f2bf(f[4]) | ((unsigned)f2bf(f[5]) << 16);
    o.w = (unsigned)f2bf(f[6]) | ((unsigned)f2bf(f[7]) << 16);
    ((uint4*)A1)[idx] = o;
}

extern "C" void kernel_launch(void* const* d_in, const int* in_sizes, int n_in,
                              void* d_out, int out_size, void* d_ws, size_t ws_size,
                              hipStream_t stream) {
    const float* x     = (const float*)d_in[0];
    const int*   ei    = (const int*)d_in[1];
    const float* W1l   = (const float*)d_in[2];
    const float* b1    = (const float*)d_in[3];
    const float* W1r   = (const float*)d_in[4];
    const float* gamma = (const float*)d_in[5];
    const float* beta  = (const float*)d_in[6];
    const float* W2l   = (const float*)d_in[7];
    const float* b2    = (const float*)d_in[8];
    const float* W2r   = (const float*)d_in[9];
    float* out = (float*)d_out;

    // workspace layout (~30.3 MB; pairs aliases hpreb)
    char* wsb = (char*)d_ws;
    int*   gcur   = (int*)wsb;                                   // 256
    float* sums   = (float*)(gcur + 256);                        // 128
    float* sumsq  = sums + 128;                                  // 128
    int*   startp = (int*)(sums + 256);                          // NN
    int*   endp   = startp + NN;                                 // NN
    int*   perm   = endp + NN;                                   // NBK*CAP
    unsigned short* A1    = (unsigned short*)(perm + NBK * CAP); // NN*128 bf16
    unsigned short* hpreb = A1 + (size_t)NN * 128;               // NN*128 bf16; reused as pb
    unsigned short* BT1   = hpreb + (size_t)NN * 128;            // 128*128 bf16
    unsigned short* BT2   = BT1 + 128 * 128;                     // 128*128 bf16
    int2*  pairs  = (int2*)hpreb;                                // NBK*CAP int2 (dead before conv1)

    const int* srcp = ei;
    const int* dstp = ei + NE;

    const int GB = (NN * 64 + 255) / 256;   // one wave per node
    const int CB = 512;                     // conv grid

    prep_kernel<<<XB + 64 + 1, 256, 0, stream>>>(x, A1, W1l, W1r, W2l, W2r,
                                                 BT1, BT2, gcur, sums);
    binA_kernel<<<HB, 256, 0, stream>>>(srcp, dstp, gcur, pairs);
    binB_kernel<<<NBK, 256, 0, stream>>>(pairs, gcur, startp, endp, perm);

    // agg1: gather A1 x-half (cols 64:128) -> bf16 mean into A1 cols 0:64
    agg_gather_b<0><<<GB, 256, 0, stream>>>(A1, 128, 64, startp, endp, perm,
                                            A1, 128, 0, nullptr);
    // conv1: hpre = A1 @ [W1l;W1r] + b1 ; packed bf16 store + fp32 BN stats
    conv_mfma_kernel<true><<<CB, 256, 0, stream>>>(A1, BT1, b1, hpreb, nullptr, sums, sumsq);
    // h = relu(bn(hpreb)) -> A1  (stats->scale/shift computed per-block in LDS)
    bnapply_kernel<<<XB, 256, 0, stream>>>(hpreb, sums, sumsq, gamma, beta, A1);
    // conv2: [p | self] = A1 @ [W2l|W2r] ; p bf16 -> hpreb(=pb), self+b2 -> out
    conv_mfma_kernel<false><<<CB, 256, 0, stream>>>(A1, BT2, b2, hpreb, out, nullptr, nullptr);
    // agg2: gather pb rows -> out += mean
    agg_gather_b<1><<<GB, 256, 0, stream>>>(hpreb, 64, 0, startp, endp, perm,
                                            nullptr, 0, 0, out);
}